// Round 1
// baseline (426.517 us; speedup 1.0000x reference)
//
#include <hip/hip_runtime.h>

// NodeLevelPromptRefiner: out = relu(concat(nf, prompt[bidx]) @ W1 + b1) @ W2 + b2
// Strategy: bf16 MFMA (16x16x32), m97-style 128x128 tile, BK=64,
// XOR-swizzled LDS (chunk ^= row&7 on 128B rows), global_load_lds w/ pre-swizzled src.

#define N_NODES   100000
#define NODE_DIM  512
#define PROMPT_DIM 512
#define N_GRAPHS  1024
#define K1        1024      // NODE_DIM + PROMPT_DIM
#define DOUT      512

#define BM 128
#define BN 128
#define BK 64
#define MT1 ((N_NODES + BM - 1) / BM)   // 782 m-tiles

typedef __bf16 bf16x8 __attribute__((ext_vector_type(8)));
typedef float  f32x4  __attribute__((ext_vector_type(4)));
typedef unsigned short ushort_t;
typedef unsigned int uint_t;

__device__ __forceinline__ ushort_t f2bf(float f) {
  __bf16 b = (__bf16)f;                       // RNE cvt, compiler emits v_cvt
  return __builtin_bit_cast(unsigned short, b);
}

__device__ __forceinline__ void gload_lds16(const void* g, void* l) {
  __builtin_amdgcn_global_load_lds(
      (const __attribute__((address_space(1))) void*)g,
      (__attribute__((address_space(3))) void*)l,
      16, 0, 0);
}

// ---------------- prep: bf16 conversions + weight transposes into ws ----------------
// prm[g*512+d]   = bf16(graph_prompt[g*512+d])
// W1T[n*1024+k]  = bf16(W1[k*512+n])
// W2T[n*512+k]   = bf16(W2[k*512+n])
__global__ void prep_kernel(const float* __restrict__ gp, const float* __restrict__ W1,
                            const float* __restrict__ W2, ushort_t* __restrict__ prm,
                            ushort_t* __restrict__ W1T, ushort_t* __restrict__ W2T) {
  int i = blockIdx.x * 256 + threadIdx.x;
  if (i < 524288) {
    prm[i] = f2bf(gp[i]);
  } else if (i < 1048576) {
    int j = i - 524288;
    int n = j >> 10, k = j & 1023;
    W1T[j] = f2bf(W1[k * 512 + n]);
  } else if (i < 1310720) {
    int j = i - 1048576;
    int n = j >> 9, k = j & 511;
    W2T[j] = f2bf(W2[k * 512 + n]);
  }
}

// ---------------- GEMM1: h = relu(A @ W1 + b1), A = [nf | prm[bidx]] ----------------
__global__ __launch_bounds__(256, 2) void gemm1_kernel(
    const float* __restrict__ nf, const int* __restrict__ bidx,
    const ushort_t* __restrict__ prm, const ushort_t* __restrict__ W1T,
    const float* __restrict__ bias1, ushort_t* __restrict__ h) {
  __shared__ ushort_t sA[BM * BK];   // [row 128][k 64] bf16, chunk-swizzled
  __shared__ ushort_t sB[BN * BK];   // [col 128][k 64] bf16 (B^T), chunk-swizzled

  const int tid = threadIdx.x;
  const int lane = tid & 63;
  const int wid = tid >> 6;
  const int mt = blockIdx.x >> 2;
  const int nt = blockIdx.x & 3;
  const int m0 = mt * BM;
  const int n0 = nt * BN;

  // A staging: 4 chunks (16B) per thread, reg-staged (needs fp32->bf16 / gather)
  const float* pnode[4];
  const ushort_t* pprm[4];
  int ldsA[4];
  for (int s = 0; s < 4; ++s) {
    int q = tid + s * 256;          // chunk id: row=q>>3, phys chunk=q&7
    int row = q >> 3;
    int cw = (q & 7) ^ (row & 7);   // logical k-chunk stored at this phys slot
    int rowg = m0 + row;
    if (rowg > N_NODES - 1) rowg = N_NODES - 1;     // tail clamp (masked at store)
    pnode[s] = nf + (size_t)rowg * NODE_DIM + cw * 8;
    int g = bidx[rowg];
    pprm[s] = prm + (size_t)g * PROMPT_DIM + cw * 8;
    ldsA[s] = q * 8;                // ushort index (16B per chunk)
  }
  // B staging: global_load_lds, wave-uniform LDS base + lane*16, pre-swizzled src
  const ushort_t* pB[4];
  int ldsB[4];
  for (int s = 0; s < 4; ++s) {
    int q = wid * 256 + s * 64 + lane;
    int row = q >> 3;
    int cw = (q & 7) ^ (row & 7);
    pB[s] = W1T + (size_t)(n0 + row) * K1 + cw * 8;
    ldsB[s] = (wid * 256 + s * 64) * 8;   // wave-uniform
  }

  f32x4 acc[4][4];
#pragma unroll
  for (int i = 0; i < 4; ++i)
#pragma unroll
    for (int j = 0; j < 4; ++j) acc[i][j] = {0.f, 0.f, 0.f, 0.f};

  const int wm = (wid >> 1) * 64;
  const int wn = (wid & 1) * 64;
  const int lr = lane >> 4;   // k-chunk select / row-quad select
  const int lc = lane & 15;

  for (int kt = 0; kt < K1 / BK; ++kt) {
#pragma unroll
    for (int s = 0; s < 4; ++s) {    // B: async global->LDS
      gload_lds16(pB[s], &sB[ldsB[s]]);
      pB[s] += BK;
    }
    if (kt < 8) {                    // A from node_feats (fp32 -> bf16)
#pragma unroll
      for (int s = 0; s < 4; ++s) {
        float4 x = *(const float4*)(pnode[s]);
        float4 y = *(const float4*)(pnode[s] + 4);
        pnode[s] += BK;
        bf16x8 v;
        v[0] = (__bf16)x.x; v[1] = (__bf16)x.y; v[2] = (__bf16)x.z; v[3] = (__bf16)x.w;
        v[4] = (__bf16)y.x; v[5] = (__bf16)y.y; v[6] = (__bf16)y.z; v[7] = (__bf16)y.w;
        *(bf16x8*)&sA[ldsA[s]] = v;
      }
    } else {                         // A from gathered prompt (already bf16)
#pragma unroll
      for (int s = 0; s < 4; ++s) {
        bf16x8 v = *(const bf16x8*)(pprm[s]);
        pprm[s] += BK;
        *(bf16x8*)&sA[ldsA[s]] = v;
      }
    }
    __syncthreads();                 // drains vmcnt (gload_lds) + lgkm (ds_write)

#pragma unroll
    for (int kk = 0; kk < 2; ++kk) {
      bf16x8 af[4], bfr[4];
#pragma unroll
      for (int i = 0; i < 4; ++i) {
        int row = wm + i * 16 + lc;
        int cp = (kk * 4 + lr) ^ (row & 7);
        af[i] = *(const bf16x8*)&sA[row * BK + cp * 8];
      }
#pragma unroll
      for (int j = 0; j < 4; ++j) {
        int col = wn + j * 16 + lc;
        int cp = (kk * 4 + lr) ^ (col & 7);
        bfr[j] = *(const bf16x8*)&sB[col * BK + cp * 8];
      }
#pragma unroll
      for (int i = 0; i < 4; ++i)
#pragma unroll
        for (int j = 0; j < 4; ++j)
          acc[i][j] = __builtin_amdgcn_mfma_f32_16x16x32_bf16(af[i], bfr[j], acc[i][j], 0, 0, 0);
    }
    __syncthreads();
  }

  // epilogue: +bias1, relu, bf16 store to h
#pragma unroll
  for (int j = 0; j < 4; ++j) {
    int col = n0 + wn + j * 16 + lc;
    float b1 = bias1[col];
#pragma unroll
    for (int i = 0; i < 4; ++i) {
      int rowb = m0 + wm + i * 16 + lr * 4;
#pragma unroll
      for (int r = 0; r < 4; ++r) {
        int row = rowb + r;
        if (row < N_NODES) {
          float v = fmaxf(acc[i][j][r] + b1, 0.f);
          h[(size_t)row * DOUT + col] = f2bf(v);
        }
      }
    }
  }
}

// ---------------- GEMM2: out = h @ W2 + b2 (fp32 out) ----------------
__global__ __launch_bounds__(256, 2) void gemm2_kernel(
    const ushort_t* __restrict__ h, const ushort_t* __restrict__ W2T,
    const float* __restrict__ bias2, float* __restrict__ out) {
  __shared__ ushort_t sA[BM * BK];
  __shared__ ushort_t sB[BN * BK];

  const int tid = threadIdx.x;
  const int lane = tid & 63;
  const int wid = tid >> 6;
  const int mt = blockIdx.x >> 2;
  const int nt = blockIdx.x & 3;
  const int m0 = mt * BM;
  const int n0 = nt * BN;

  const ushort_t* pA[4];
  const ushort_t* pB[4];
  int ldsW[4];
  for (int s = 0; s < 4; ++s) {
    int q = wid * 256 + s * 64 + lane;
    int row = q >> 3;
    int cw = (q & 7) ^ (row & 7);
    int rowg = m0 + row;
    if (rowg > N_NODES - 1) rowg = N_NODES - 1;
    pA[s] = h + (size_t)rowg * DOUT + cw * 8;
    pB[s] = W2T + (size_t)(n0 + row) * DOUT + cw * 8;
    ldsW[s] = (wid * 256 + s * 64) * 8;   // wave-uniform
  }

  f32x4 acc[4][4];
#pragma unroll
  for (int i = 0; i < 4; ++i)
#pragma unroll
    for (int j = 0; j < 4; ++j) acc[i][j] = {0.f, 0.f, 0.f, 0.f};

  const int wm = (wid >> 1) * 64;
  const int wn = (wid & 1) * 64;
  const int lr = lane >> 4;
  const int lc = lane & 15;

  for (int kt = 0; kt < DOUT / BK; ++kt) {
#pragma unroll
    for (int s = 0; s < 4; ++s) {
      gload_lds16(pA[s], &sA[ldsW[s]]);
      pA[s] += BK;
      gload_lds16(pB[s], &sB[ldsW[s]]);
      pB[s] += BK;
    }
    __syncthreads();

#pragma unroll
    for (int kk = 0; kk < 2; ++kk) {
      bf16x8 af[4], bfr[4];
#pragma unroll
      for (int i = 0; i < 4; ++i) {
        int row = wm + i * 16 + lc;
        int cp = (kk * 4 + lr) ^ (row & 7);
        af[i] = *(const bf16x8*)&sA[row * BK + cp * 8];
      }
#pragma unroll
      for (int j = 0; j < 4; ++j) {
        int col = wn + j * 16 + lc;
        int cp = (kk * 4 + lr) ^ (col & 7);
        bfr[j] = *(const bf16x8*)&sB[col * BK + cp * 8];
      }
#pragma unroll
      for (int i = 0; i < 4; ++i)
#pragma unroll
        for (int j = 0; j < 4; ++j)
          acc[i][j] = __builtin_amdgcn_mfma_f32_16x16x32_bf16(af[i], bfr[j], acc[i][j], 0, 0, 0);
    }
    __syncthreads();
  }

#pragma unroll
  for (int j = 0; j < 4; ++j) {
    int col = n0 + wn + j * 16 + lc;
    float b2 = bias2[col];
#pragma unroll
    for (int i = 0; i < 4; ++i) {
      int rowb = m0 + wm + i * 16 + lr * 4;
#pragma unroll
      for (int r = 0; r < 4; ++r) {
        int row = rowb + r;
        if (row < N_NODES) out[(size_t)row * DOUT + col] = acc[i][j][r] + b2;
      }
    }
  }
}

extern "C" void kernel_launch(void* const* d_in, const int* in_sizes, int n_in,
                              void* d_out, int out_size, void* d_ws, size_t ws_size,
                              hipStream_t stream) {
  const float* nf   = (const float*)d_in[0];   // [100000,512] f32
  const float* gp   = (const float*)d_in[1];   // [1024,512]  f32
  const int*   bidx = (const int*)d_in[2];     // [100000]    i32 (sorted)
  const float* W1   = (const float*)d_in[3];   // [1024,512]  f32
  const float* b1   = (const float*)d_in[4];   // [512]
  const float* W2   = (const float*)d_in[5];   // [512,512]   f32
  const float* b2   = (const float*)d_in[6];   // [512]
  float* out = (float*)d_out;

  char* ws = (char*)d_ws;
  ushort_t* h_buf = (ushort_t*)ws;                    // 102,400,000 B
  ushort_t* W1T   = (ushort_t*)(ws + 102400000);      //   1,048,576 B
  ushort_t* W2T   = (ushort_t*)(ws + 103448576);      //     524,288 B
  ushort_t* prm   = (ushort_t*)(ws + 103972864);      //   1,048,576 B (total ~105 MB)

  prep_kernel<<<5120, 256, 0, stream>>>(gp, W1, W2, prm, W1T, W2T);
  gemm1_kernel<<<MT1 * 4, 256, 0, stream>>>(nf, bidx, prm, W1T, b1, h_buf);
  gemm2_kernel<<<MT1 * 4, 256, 0, stream>>>(h_buf, W2T, b2, out);
}

// Round 2
// 310.809 us; speedup vs baseline: 1.3723x; 1.3723x over previous
//
#include <hip/hip_runtime.h>

// out = relu(concat(nf, prompt[bidx]) @ W1 + b1) @ W2 + b2
// Decomposition:
//   P2[g]  = prompt[g] @ W1[512:,:] + b1          (1024x512, tiny GEMM)
//   h      = relu(nf @ W1[:512,:] + P2[bidx])     (fused, h stays on-chip)
//   out    = h @ W2 + b2                          (fused, W2^T frags from L2)

#define N_NODES   100000

typedef __bf16 bf16x8 __attribute__((ext_vector_type(8)));
typedef float  f32x4  __attribute__((ext_vector_type(4)));
typedef unsigned short ushort_t;

__device__ __forceinline__ ushort_t f2bf(float f) {
  __bf16 b = (__bf16)f;
  return __builtin_bit_cast(unsigned short, b);
}

__device__ __forceinline__ void gload_lds16(const void* g, void* l) {
  __builtin_amdgcn_global_load_lds(
      (const __attribute__((address_space(1))) void*)g,
      (__attribute__((address_space(3))) void*)l, 16, 0, 0);
}

// ---------------- prep: bf16 conversions + weight transposes ----------------
__global__ void prep_kernel(const float* __restrict__ gp, const float* __restrict__ W1,
                            const float* __restrict__ W2, ushort_t* __restrict__ prm,
                            ushort_t* __restrict__ W1T, ushort_t* __restrict__ W2T) {
  int i = blockIdx.x * 256 + threadIdx.x;
  if (i < 524288) {
    prm[i] = f2bf(gp[i]);                       // prm[g*512+k]
  } else if (i < 1048576) {
    int j = i - 524288;
    int n = j >> 10, k = j & 1023;
    W1T[j] = f2bf(W1[k * 512 + n]);             // W1T[n*1024+k]
  } else if (i < 1310720) {
    int j = i - 1048576;
    int n = j >> 9, k = j & 511;
    W2T[j] = f2bf(W2[k * 512 + n]);             // W2T[n*512+k]
  }
}

// ---------------- P2[g][n] = prm[g] @ W1[512+k][n] + bias1[n] ----------------
__global__ __launch_bounds__(256, 2) void p2_kernel(
    const ushort_t* __restrict__ prm, const ushort_t* __restrict__ W1T,
    const float* __restrict__ bias1, float* __restrict__ P2) {
  __shared__ ushort_t sA[128 * 64];
  __shared__ ushort_t sB[128 * 64];
  const int tid = threadIdx.x, lane = tid & 63, wid = tid >> 6;
  const int m0 = (blockIdx.x >> 2) * 128, n0 = (blockIdx.x & 3) * 128;

  const ushort_t* pA[4]; const ushort_t* pB[4]; int ldsW[4];
#pragma unroll
  for (int s = 0; s < 4; ++s) {
    int q = wid * 256 + s * 64 + lane;
    int row = q >> 3;
    int cw = (q & 7) ^ (row & 7);
    pA[s] = prm + (size_t)(m0 + row) * 512 + cw * 8;
    pB[s] = W1T + (size_t)(n0 + row) * 1024 + 512 + cw * 8;   // k-offset 512 (W1b)
    ldsW[s] = (wid * 256 + s * 64) * 8;
  }
  f32x4 acc[4][4];
#pragma unroll
  for (int i = 0; i < 4; ++i)
#pragma unroll
    for (int j = 0; j < 4; ++j) acc[i][j] = {0.f, 0.f, 0.f, 0.f};
  const int wm = (wid >> 1) * 64, wn = (wid & 1) * 64;
  const int lr = lane >> 4, lc = lane & 15;

  for (int kt = 0; kt < 8; ++kt) {
#pragma unroll
    for (int s = 0; s < 4; ++s) {
      gload_lds16(pA[s], &sA[ldsW[s]]); pA[s] += 64;
      gload_lds16(pB[s], &sB[ldsW[s]]); pB[s] += 64;
    }
    __syncthreads();
#pragma unroll
    for (int kk = 0; kk < 2; ++kk) {
      bf16x8 af[4], bfr[4];
#pragma unroll
      for (int i = 0; i < 4; ++i) {
        int row = wm + i * 16 + lc;
        int cp = (kk * 4 + lr) ^ (row & 7);
        af[i] = *(const bf16x8*)&sA[row * 64 + cp * 8];
      }
#pragma unroll
      for (int j = 0; j < 4; ++j) {
        int col = wn + j * 16 + lc;
        int cp = (kk * 4 + lr) ^ (col & 7);
        bfr[j] = *(const bf16x8*)&sB[col * 64 + cp * 8];
      }
#pragma unroll
      for (int i = 0; i < 4; ++i)
#pragma unroll
        for (int j = 0; j < 4; ++j)
          acc[i][j] = __builtin_amdgcn_mfma_f32_16x16x32_bf16(af[i], bfr[j], acc[i][j], 0, 0, 0);
    }
    __syncthreads();
  }
#pragma unroll
  for (int j = 0; j < 4; ++j) {
    int col = n0 + wn + j * 16 + lc;
    float bv = bias1[col];
#pragma unroll
    for (int i = 0; i < 4; ++i)
#pragma unroll
      for (int r = 0; r < 4; ++r) {
        int row = m0 + wm + i * 16 + lr * 4 + r;
        P2[(size_t)row * 512 + col] = acc[i][j][r] + bv;
      }
  }
}

// ---------------- fused: out[64xblock] = relu(nf@W1a + P2[bidx]) @ W2 + b2 ----------------
__global__ __launch_bounds__(512, 4) void fused_kernel(
    const float* __restrict__ nf, const int* __restrict__ bidx,
    const ushort_t* __restrict__ W1T, const float* __restrict__ P2,
    const ushort_t* __restrict__ W2T, const float* __restrict__ bias2,
    float* __restrict__ out) {
  __shared__ ushort_t sA[2][64 * 64];   // 2 x 8 KB A-panels [row][k64] swizzled
  __shared__ ushort_t sH[64 * 512];     // 64 KB h tile [row][c512] swizzled
  // total LDS = 80 KB -> 2 blocks/CU

  const int tid = threadIdx.x;
  const int lane = tid & 63;
  const int cg = tid >> 6;              // wave = col-group 0..7 (64 cols each)
  const int lc = lane & 15, lr = lane >> 4;
  const int m0 = blockIdx.x * 64;

  // ---- A staging assignment: 1 chunk (16B bf16 = 8 elems) per thread per panel
  const int arow = tid >> 3;            // 0..63
  const int aslot = tid & 7;            // physical chunk slot in row
  const int aclog = aslot ^ (arow & 7); // logical k-chunk stored at this slot
  int arowg = m0 + arow; if (arowg > N_NODES - 1) arowg = N_NODES - 1;
  const float* abase = nf + (size_t)arowg * 512 + aclog * 8;

  // prologue: stage panel 0
  {
    float4 x = *(const float4*)(abase);
    float4 y = *(const float4*)(abase + 4);
    bf16x8 v;
    v[0] = (__bf16)x.x; v[1] = (__bf16)x.y; v[2] = (__bf16)x.z; v[3] = (__bf16)x.w;
    v[4] = (__bf16)y.x; v[5] = (__bf16)y.y; v[6] = (__bf16)y.z; v[7] = (__bf16)y.w;
    *(bf16x8*)&sA[0][tid * 8] = v;
  }
  __syncthreads();

  // ---- GEMM1: hacc[i][j] = 64x64 h sub-tile (rows i*16.., cols cg*64 + j*16..)
  f32x4 hacc[4][4];
#pragma unroll
  for (int i = 0; i < 4; ++i)
#pragma unroll
    for (int j = 0; j < 4; ++j) hacc[i][j] = {0.f, 0.f, 0.f, 0.f};

#pragma unroll
  for (int kt = 0; kt < 8; ++kt) {
    // b1 batch first (so MFMA's vmcnt wait keeps the A-prefetch in flight)
    bf16x8 b1[2][4];
#pragma unroll
    for (int kk = 0; kk < 2; ++kk)
#pragma unroll
      for (int j = 0; j < 4; ++j)
        b1[kk][j] = *(const bf16x8*)(W1T + (size_t)(cg * 64 + j * 16 + lc) * 1024
                                     + kt * 64 + kk * 32 + lr * 8);
    // T14: issue next-panel A loads early
    float4 ax, ay;
    if (kt < 7) {
      ax = *(const float4*)(abase + (kt + 1) * 64);
      ay = *(const float4*)(abase + (kt + 1) * 64 + 4);
    }
    // compute current panel
    const ushort_t* buf = sA[kt & 1];
#pragma unroll
    for (int kk = 0; kk < 2; ++kk) {
#pragma unroll
      for (int i = 0; i < 4; ++i) {
        int row = i * 16 + lc;
        int phys = (kk * 4 + lr) ^ (row & 7);
        bf16x8 a = *(const bf16x8*)&buf[row * 64 + phys * 8];
#pragma unroll
        for (int j = 0; j < 4; ++j)
          hacc[i][j] = __builtin_amdgcn_mfma_f32_16x16x32_bf16(a, b1[kk][j], hacc[i][j], 0, 0, 0);
      }
    }
    // write next panel late, then barrier
    if (kt < 7) {
      bf16x8 v;
      v[0] = (__bf16)ax.x; v[1] = (__bf16)ax.y; v[2] = (__bf16)ax.z; v[3] = (__bf16)ax.w;
      v[4] = (__bf16)ay.x; v[5] = (__bf16)ay.y; v[6] = (__bf16)ay.z; v[7] = (__bf16)ay.w;
      *(bf16x8*)&sA[(kt + 1) & 1][tid * 8] = v;
      __syncthreads();
    }
  }

  // ---- epi1: h = relu(hacc + P2[bidx]) -> sH (bf16, swizzled [row][64 chunks])
#pragma unroll
  for (int i = 0; i < 4; ++i) {
#pragma unroll
    for (int r = 0; r < 4; ++r) {
      int row = i * 16 + lr * 4 + r;
      int rowg = m0 + row; if (rowg > N_NODES - 1) rowg = N_NODES - 1;
      int g = bidx[rowg];
      const float* p2row = P2 + (size_t)g * 512;
#pragma unroll
      for (int j = 0; j < 4; ++j) {
        int col = cg * 64 + j * 16 + lc;
        float v = fmaxf(hacc[i][j][r] + p2row[col], 0.f);
        int c = col >> 3;
        int phys = (c & 48) | ((c ^ row) & 15);
        *(__bf16*)((char*)sH + row * 1024 + phys * 16 + (col & 7) * 2) = (__bf16)v;
      }
    }
  }
  __syncthreads();

  // ---- GEMM2: oacc[i][j] = out sub-tile (rows i*16.., cols cg*64 + j*16..)
  f32x4 oacc[4][4];
#pragma unroll
  for (int i = 0; i < 4; ++i)
#pragma unroll
    for (int j = 0; j < 4; ++j) oacc[i][j] = {0.f, 0.f, 0.f, 0.f};

#pragma unroll
  for (int kk = 0; kk < 16; ++kk) {
    int kl = kk * 32 + lr * 8;
    bf16x8 a2[4];
#pragma unroll
    for (int i = 0; i < 4; ++i) {
      int row = i * 16 + lc;
      int c = kk * 4 + lr;
      int phys = (c & 48) | ((c ^ row) & 15);
      a2[i] = *(const bf16x8*)&sH[row * 512 + phys * 8];
    }
#pragma unroll
    for (int j = 0; j < 4; ++j) {
      bf16x8 b2 = *(const bf16x8*)(W2T + (size_t)(cg * 64 + j * 16 + lc) * 512 + kl);
#pragma unroll
      for (int i = 0; i < 4; ++i)
        oacc[i][j] = __builtin_amdgcn_mfma_f32_16x16x32_bf16(a2[i], b2, oacc[i][j], 0, 0, 0);
    }
  }

  // ---- epi2: out = oacc + bias2
#pragma unroll
  for (int j = 0; j < 4; ++j) {
    int col = cg * 64 + j * 16 + lc;
    float bv = bias2[col];
#pragma unroll
    for (int i = 0; i < 4; ++i)
#pragma unroll
      for (int r = 0; r < 4; ++r) {
        int rowg = m0 + i * 16 + lr * 4 + r;
        if (rowg < N_NODES)
          out[(size_t)rowg * 512 + col] = oacc[i][j][r] + bv;
      }
  }
}

extern "C" void kernel_launch(void* const* d_in, const int* in_sizes, int n_in,
                              void* d_out, int out_size, void* d_ws, size_t ws_size,
                              hipStream_t stream) {
  const float* nf   = (const float*)d_in[0];   // [100000,512] f32
  const float* gp   = (const float*)d_in[1];   // [1024,512]  f32
  const int*   bidx = (const int*)d_in[2];     // [100000]    i32 (sorted)
  const float* W1   = (const float*)d_in[3];   // [1024,512]  f32
  const float* b1   = (const float*)d_in[4];   // [512]
  const float* W2   = (const float*)d_in[5];   // [512,512]   f32
  const float* b2   = (const float*)d_in[6];   // [512]
  float* out = (float*)d_out;

  char* ws = (char*)d_ws;
  ushort_t* prm = (ushort_t*)ws;                    // 1,048,576 B
  ushort_t* W1T = (ushort_t*)(ws + 1048576);        // 1,048,576 B
  ushort_t* W2T = (ushort_t*)(ws + 2097152);        //   524,288 B
  float*    P2  = (float*)   (ws + 2621440);        // 2,097,152 B  (total ~4.5 MB)

  prep_kernel<<<5120, 256, 0, stream>>>(gp, W1, W2, prm, W1T, W2T);
  p2_kernel<<<32, 256, 0, stream>>>(prm, W1T, b1, P2);
  fused_kernel<<<(N_NODES + 63) / 64, 512, 0, stream>>>(nf, bidx, W1T, P2, W2T, b2, out);
}